// Round 3
// baseline (76.821 us; speedup 1.0000x reference)
//
#include <hip/hip_runtime.h>

// Flash attention fwd, fp32 in/out, f16 MFMA compute, per-batch key masking.
// B=16, LQ=LK=2048, D=64. Swapped QK^T (S^T = K*Q) so softmax is lane-local;
// PV consumes P directly from S^T C-layout registers (slot-consistent with a
// matching Vt LDS read order) -> zero cross-lane shuffles in the main loop.
//
// R2: split-K (flash-decoding) over NSPLIT=4 key ranges + combine kernel.
//     Fixes the same-batch-per-CU imbalance (64 tiles worst-case CU -> ~33)
//     and raises occupancy 8 -> 32 waves/CU. Falls back to single-kernel
//     if ws_size is too small.

namespace {

constexpr int NB  = 16;
constexpr int SLQ = 2048;
constexpr int SLK = 2048;
constexpr int DH  = 64;
constexpr int KB  = 64;   // key tile
constexpr int QB  = 64;   // q rows per block (4 waves x 16)
constexpr int KST = 72;   // K lds row stride (halves) -> 144B, breaks 128B bank aliasing
constexpr int VST = 76;   // Vt lds row stride (halves) -> 152B, 8B-aligned for b64

constexpr int NSPLIT = 4;
constexpr int TPS    = 8;    // key tiles per split (32 max tiles / 4)

typedef _Float16 half8  __attribute__((ext_vector_type(8)));
typedef _Float16 half4  __attribute__((ext_vector_type(4)));
typedef _Float16 half2t __attribute__((ext_vector_type(2)));
typedef float    f32x4  __attribute__((ext_vector_type(4)));

__device__ inline half2t pkrtz(float a, float b) {
    return __builtin_bit_cast(half2t, __builtin_amdgcn_cvt_pkrtz(a, b));
}

__global__ __launch_bounds__(256, 8)
void attn_fwd(const float* __restrict__ qg, const float* __restrict__ kg,
              const float* __restrict__ vg, const int* __restrict__ vn,
              float* __restrict__ og,
              float* __restrict__ ws_acc, float* __restrict__ ws_ml,
              int split)
{
    __shared__ _Float16 Kl[KB][KST];   // K tile, [key][d]
    __shared__ _Float16 Vt[DH][VST];   // V tile transposed, [d][key]

    const int t   = threadIdx.x;
    const int l   = t & 63;
    const int w   = t >> 6;     // wave id 0..3
    const int q15 = l & 15;     // q col within wave's 16 rows (C-layout col)
    const int g   = l >> 4;     // lane group 0..3

    const int bid = blockIdx.x;
    int b, qt, s;
    if (split) {
        // mix batches within each 256-block dispatch stripe: b depends on qt
        qt = bid >> 6;                        // 0..31
        s  = bid & 3;                         // key-range split 0..3
        b  = (((bid >> 2) & 15) + qt) & 15;   // bijective per qt
    } else {
        b  = bid & (NB - 1);
        qt = bid >> 4;
        s  = 0;
    }

    const int valid = vn[b];
    const int nkt   = (valid + KB - 1) / KB;   // skip fully-masked key tiles
    const int kt0   = s * TPS;
    if (split && kt0 >= nkt) return;           // whole block inactive (uniform)
    const int kt1   = split ? min(nkt, kt0 + TPS) : nkt;

    const int qrow = qt * QB + w * 16 + q15;

    // fold 1/sqrt(D)=1/8 and log2(e) into Q so scores are already in log2 units
    const float QS = 0.18033688011112042f;  // log2(e)/8

    // Q fragment (B-operand layout: col=q15, k(d)=8g+32s+j), kept in regs
    half8 qf[2];
    {
        const float* qp = qg + ((size_t)b * SLQ + qrow) * DH;
#pragma unroll
        for (int ss = 0; ss < 2; ++ss) {
            const int d0 = 8 * g + 32 * ss;
            f32x4 x = *(const f32x4*)(qp + d0);
            f32x4 y = *(const f32x4*)(qp + d0 + 4);
            half8 h;
#pragma unroll
            for (int i = 0; i < 4; ++i) {
                h[i]     = (_Float16)(x[i] * QS);
                h[i + 4] = (_Float16)(y[i] * QS);
            }
            qf[ss] = h;
        }
    }

    // out^T accumulators: acc[mt][r] = out[q15][16*mt + 4*g + r]
    f32x4 acc[4];
#pragma unroll
    for (int i = 0; i < 4; ++i) acc[i] = f32x4{0.f, 0.f, 0.f, 0.f};

    float m    = -1e30f;
    float lsum = 0.f;

    const float* kbp = kg + (size_t)b * SLK * DH;
    const float* vbp = vg + (size_t)b * SLK * DH;

    for (int kt = kt0; kt < kt1; ++kt) {
        __syncthreads();   // previous tile's LDS reads done before overwrite

        // ---- stage K tile: 256 threads, each 1 row-quarter (16 f32 -> 16 f16)
        {
            const int row = t >> 2;
            const int d0  = (t & 3) * 16;
            const float* kp = kbp + (size_t)(kt * KB + row) * DH + d0;
            f32x4 a0 = *(const f32x4*)(kp);
            f32x4 a1 = *(const f32x4*)(kp + 4);
            f32x4 a2 = *(const f32x4*)(kp + 8);
            f32x4 a3 = *(const f32x4*)(kp + 12);
            half8 h0, h1;
#pragma unroll
            for (int i = 0; i < 4; ++i) {
                h0[i]     = (_Float16)a0[i];
                h0[i + 4] = (_Float16)a1[i];
                h1[i]     = (_Float16)a2[i];
                h1[i + 4] = (_Float16)a3[i];
            }
            *(half8*)&Kl[row][d0]     = h0;
            *(half8*)&Kl[row][d0 + 8] = h1;
        }
        // ---- stage V transposed: thread owns keys {kk,kk+1} x 4 d's x 2 passes
        {
            const int kk = (t & 31) * 2;
            const int db = (t >> 5) * 4;
#pragma unroll
            for (int dd = 0; dd < 2; ++dd) {
                const int d0 = db + 32 * dd;
                const float* vp = vbp + (size_t)(kt * KB + kk) * DH + d0;
                f32x4 r0 = *(const f32x4*)(vp);
                f32x4 r1 = *(const f32x4*)(vp + DH);
#pragma unroll
                for (int i = 0; i < 4; ++i) {
                    // Vt[d][kk..kk+1] = {V[kk][d], V[kk+1][d]} ; 2-way-free banks
                    *(half2t*)&Vt[d0 + i][kk] = pkrtz(r0[i], r1[i]);
                }
            }
        }
        __syncthreads();

        // ---- QK^T (swapped): st[mt] C-layout: col=q15, row=key 16mt+4g+r
        f32x4 st[4];
#pragma unroll
        for (int mt = 0; mt < 4; ++mt) {
            f32x4 c = f32x4{0.f, 0.f, 0.f, 0.f};
#pragma unroll
            for (int ss = 0; ss < 2; ++ss) {
                half8 a = *(const half8*)&Kl[16 * mt + q15][8 * g + 32 * ss];
                c = __builtin_amdgcn_mfma_f32_16x16x32_f16(a, qf[ss], c, 0, 0, 0);
            }
            st[mt] = c;
        }

        // ---- mask the (only) partial boundary tile
        const int krem = valid - kt * KB;
        if (krem < KB) {
#pragma unroll
            for (int mt = 0; mt < 4; ++mt)
#pragma unroll
                for (int r = 0; r < 4; ++r)
                    if (16 * mt + 4 * g + r >= krem) st[mt][r] = -1e30f;
        }

        // ---- online softmax (scores already in log2 units)
        float tmax = -1e30f;
#pragma unroll
        for (int mt = 0; mt < 4; ++mt)
#pragma unroll
            for (int r = 0; r < 4; ++r) tmax = fmaxf(tmax, st[mt][r]);
        tmax = fmaxf(tmax, __shfl_xor(tmax, 16));
        tmax = fmaxf(tmax, __shfl_xor(tmax, 32));

        const float mn = fmaxf(m, tmax);
        const float sc = __builtin_amdgcn_exp2f(m - mn);

        float p[4][4];
        float ps = 0.f;
#pragma unroll
        for (int mt = 0; mt < 4; ++mt)
#pragma unroll
            for (int r = 0; r < 4; ++r) {
                const float e = __builtin_amdgcn_exp2f(st[mt][r] - mn);
                p[mt][r] = e;
                ps += e;
            }
        ps += __shfl_xor(ps, 16);
        ps += __shfl_xor(ps, 32);
        lsum = lsum * sc + ps;
        m = mn;
#pragma unroll
        for (int mt = 0; mt < 4; ++mt) acc[mt] *= sc;

        // ---- pack P to f16 (stays in registers; key id carried by slot order)
        half2t pk[4][2];
#pragma unroll
        for (int mt = 0; mt < 4; ++mt)
#pragma unroll
            for (int rr = 0; rr < 2; ++rr)
                pk[mt][rr] = pkrtz(p[mt][2 * rr], p[mt][2 * rr + 1]);

        // ---- PV: out^T += Vt * P^T. B-slot (g,j) carries key 32ss+16(j>>2)+4g+(j&3);
        //      A (Vt) is read in exactly that key order -> slot-consistent, no shuffles.
#pragma unroll
        for (int ss = 0; ss < 2; ++ss) {
            union { half2t h2[4]; half8 v; } bf;
            bf.h2[0] = pk[2 * ss][0];
            bf.h2[1] = pk[2 * ss][1];
            bf.h2[2] = pk[2 * ss + 1][0];
            bf.h2[3] = pk[2 * ss + 1][1];
#pragma unroll
            for (int mt = 0; mt < 4; ++mt) {
                union { half4 h4[2]; half8 v; } af;
                af.h4[0] = *(const half4*)&Vt[16 * mt + q15][32 * ss + 4 * g];
                af.h4[1] = *(const half4*)&Vt[16 * mt + q15][32 * ss + 16 + 4 * g];
                acc[mt] = __builtin_amdgcn_mfma_f32_16x16x32_f16(af.v, bf.v, acc[mt], 0, 0, 0);
            }
        }
    }

    if (!split) {
        // ---- epilogue: divide by softmax denom, store float4 per d-tile
        const float inv = 1.0f / lsum;
        float* op = og + ((size_t)b * SLQ + qrow) * DH;
#pragma unroll
        for (int mt = 0; mt < 4; ++mt) {
            f32x4 o;
#pragma unroll
            for (int r = 0; r < 4; ++r) o[r] = acc[mt][r] * inv;
            *(f32x4*)(op + 16 * mt + 4 * g) = o;
        }
    } else {
        // ---- split epilogue: store unnormalized acc + (m, l) to workspace
        const size_t row = (size_t)b * SLQ + qrow;
        float* wp = ws_acc + ((size_t)s * NB * SLQ + row) * DH;
#pragma unroll
        for (int mt = 0; mt < 4; ++mt)
            *(f32x4*)(wp + 16 * mt + 4 * g) = acc[mt];
        if (g == 0) {
            float2 ml = make_float2(m, lsum);
            *(float2*)(ws_ml + ((size_t)s * NB * SLQ + row) * 2) = ml;
        }
    }
}

__global__ __launch_bounds__(256)
void attn_combine(const float* __restrict__ ws_acc, const float* __restrict__ ws_ml,
                  const int* __restrict__ vn, float* __restrict__ og)
{
    const int tid = blockIdx.x * 256 + threadIdx.x;
    const int row = tid >> 2;            // global q-row 0..32767
    const int dq  = (tid & 3) << 4;      // 16-d chunk
    const int b   = row >> 11;

    const int valid = vn[b];
    const int nkt   = (valid + KB - 1) / KB;
    const int nact  = min(NSPLIT, (nkt + TPS - 1) / TPS);

    float M = -1e30f;
    for (int s = 0; s < nact; ++s)
        M = fmaxf(M, ws_ml[((size_t)s * NB * SLQ + row) * 2]);

    float L = 0.f;
    f32x4 o[4];
#pragma unroll
    for (int i = 0; i < 4; ++i) o[i] = f32x4{0.f, 0.f, 0.f, 0.f};

    for (int s = 0; s < nact; ++s) {
        const float2 ml = *(const float2*)(ws_ml + ((size_t)s * NB * SLQ + row) * 2);
        const float wgt = __builtin_amdgcn_exp2f(ml.x - M);   // m in log2 units
        L += ml.y * wgt;
        const float* ap = ws_acc + ((size_t)s * NB * SLQ + row) * DH + dq;
#pragma unroll
        for (int i = 0; i < 4; ++i) {
            f32x4 a = *(const f32x4*)(ap + 4 * i);
            o[i] += wgt * a;
        }
    }

    const float inv = 1.0f / L;
    float* op = og + (size_t)row * DH + dq;
#pragma unroll
    for (int i = 0; i < 4; ++i) {
        f32x4 r = o[i] * inv;
        *(f32x4*)(op + 4 * i) = r;
    }
}

} // namespace

extern "C" void kernel_launch(void* const* d_in, const int* in_sizes, int n_in,
                              void* d_out, int out_size, void* d_ws, size_t ws_size,
                              hipStream_t stream)
{
    const float* q    = (const float*)d_in[0];
    const float* k    = (const float*)d_in[1];
    const float* v    = (const float*)d_in[2];
    const int*   vnum = (const int*)d_in[3];
    float* out = (float*)d_out;

    const size_t acc_elems = (size_t)NSPLIT * NB * SLQ * DH;     // 8.39M floats
    const size_t ml_elems  = (size_t)NSPLIT * NB * SLQ * 2;
    const size_t need      = (acc_elems + ml_elems) * sizeof(float);  // ~34.6 MB

    float* ws_acc = (float*)d_ws;
    float* ws_ml  = (float*)d_ws + acc_elems;

    if (ws_size >= need) {
        dim3 grid(NSPLIT * NB * (SLQ / QB));   // 2048 blocks
        attn_fwd<<<grid, dim3(256), 0, stream>>>(q, k, v, vnum, out, ws_acc, ws_ml, 1);
        attn_combine<<<dim3((NB * SLQ * 4) / 256), dim3(256), 0, stream>>>(ws_acc, ws_ml, vnum, out);
    } else {
        dim3 grid(NB * (SLQ / QB));            // 512 blocks, fallback
        attn_fwd<<<grid, dim3(256), 0, stream>>>(q, k, v, vnum, out, ws_acc, ws_ml, 0);
    }
}

// Round 4
// 68.611 us; speedup vs baseline: 1.1197x; 1.1197x over previous
//
#include <hip/hip_runtime.h>

// Flash attention fwd, fp32 in/out, f16 MFMA compute, per-batch key masking.
// B=16, LQ=LK=2048, D=64. Swapped QK^T (S^T = K*Q) so softmax is lane-local;
// PV consumes P directly from S^T C-layout registers (slot-consistent with a
// matching Vt LDS read order) -> zero cross-lane shuffles in the main loop.
//
// R2: split-K (flash-decoding) over NSPLIT=4 key ranges + combine kernel.
// R4: drop the (256,8) launch-bounds min-waves hint -- it forced VGPR 56->32
//     and spilled the accumulators to scratch (R3 regression). Plain (256)
//     compiles to ~56 VGPR which already permits 8 blocks/CU (LDS-limited).

namespace {

constexpr int NB  = 16;
constexpr int SLQ = 2048;
constexpr int SLK = 2048;
constexpr int DH  = 64;
constexpr int KB  = 64;   // key tile
constexpr int QB  = 64;   // q rows per block (4 waves x 16)
constexpr int KST = 72;   // K lds row stride (halves) -> 144B, breaks 128B bank aliasing
constexpr int VST = 76;   // Vt lds row stride (halves) -> 152B, 8B-aligned for b64

constexpr int NSPLIT = 4;
constexpr int TPS    = 8;    // key tiles per split (32 max tiles / 4)

typedef _Float16 half8  __attribute__((ext_vector_type(8)));
typedef _Float16 half4  __attribute__((ext_vector_type(4)));
typedef _Float16 half2t __attribute__((ext_vector_type(2)));
typedef float    f32x4  __attribute__((ext_vector_type(4)));

__device__ inline half2t pkrtz(float a, float b) {
    return __builtin_bit_cast(half2t, __builtin_amdgcn_cvt_pkrtz(a, b));
}

__global__ __launch_bounds__(256)
void attn_fwd(const float* __restrict__ qg, const float* __restrict__ kg,
              const float* __restrict__ vg, const int* __restrict__ vn,
              float* __restrict__ og,
              float* __restrict__ ws_acc, float* __restrict__ ws_ml,
              int split)
{
    __shared__ _Float16 Kl[KB][KST];   // K tile, [key][d]
    __shared__ _Float16 Vt[DH][VST];   // V tile transposed, [d][key]

    const int t   = threadIdx.x;
    const int l   = t & 63;
    const int w   = t >> 6;     // wave id 0..3
    const int q15 = l & 15;     // q col within wave's 16 rows (C-layout col)
    const int g   = l >> 4;     // lane group 0..3

    const int bid = blockIdx.x;
    int b, qt, s;
    if (split) {
        // mix batches within each 256-block dispatch stripe: b depends on qt
        qt = bid >> 6;                        // 0..31
        s  = bid & 3;                         // key-range split 0..3
        b  = (((bid >> 2) & 15) + qt) & 15;   // bijective per qt
    } else {
        b  = bid & (NB - 1);
        qt = bid >> 4;
        s  = 0;
    }

    const int valid = vn[b];
    const int nkt   = (valid + KB - 1) / KB;   // skip fully-masked key tiles
    const int kt0   = s * TPS;
    if (split && kt0 >= nkt) return;           // whole block inactive (uniform)
    const int kt1   = split ? min(nkt, kt0 + TPS) : nkt;

    const int qrow = qt * QB + w * 16 + q15;

    // fold 1/sqrt(D)=1/8 and log2(e) into Q so scores are already in log2 units
    const float QS = 0.18033688011112042f;  // log2(e)/8

    // Q fragment (B-operand layout: col=q15, k(d)=8g+32s+j), kept in regs
    half8 qf[2];
    {
        const float* qp = qg + ((size_t)b * SLQ + qrow) * DH;
#pragma unroll
        for (int ss = 0; ss < 2; ++ss) {
            const int d0 = 8 * g + 32 * ss;
            f32x4 x = *(const f32x4*)(qp + d0);
            f32x4 y = *(const f32x4*)(qp + d0 + 4);
            half8 h;
#pragma unroll
            for (int i = 0; i < 4; ++i) {
                h[i]     = (_Float16)(x[i] * QS);
                h[i + 4] = (_Float16)(y[i] * QS);
            }
            qf[ss] = h;
        }
    }

    // out^T accumulators: acc[mt][r] = out[q15][16*mt + 4*g + r]
    f32x4 acc[4];
#pragma unroll
    for (int i = 0; i < 4; ++i) acc[i] = f32x4{0.f, 0.f, 0.f, 0.f};

    float m    = -1e30f;
    float lsum = 0.f;

    const float* kbp = kg + (size_t)b * SLK * DH;
    const float* vbp = vg + (size_t)b * SLK * DH;

    for (int kt = kt0; kt < kt1; ++kt) {
        __syncthreads();   // previous tile's LDS reads done before overwrite

        // ---- stage K tile: 256 threads, each 1 row-quarter (16 f32 -> 16 f16)
        {
            const int row = t >> 2;
            const int d0  = (t & 3) * 16;
            const float* kp = kbp + (size_t)(kt * KB + row) * DH + d0;
            f32x4 a0 = *(const f32x4*)(kp);
            f32x4 a1 = *(const f32x4*)(kp + 4);
            f32x4 a2 = *(const f32x4*)(kp + 8);
            f32x4 a3 = *(const f32x4*)(kp + 12);
            half8 h0, h1;
#pragma unroll
            for (int i = 0; i < 4; ++i) {
                h0[i]     = (_Float16)a0[i];
                h0[i + 4] = (_Float16)a1[i];
                h1[i]     = (_Float16)a2[i];
                h1[i + 4] = (_Float16)a3[i];
            }
            *(half8*)&Kl[row][d0]     = h0;
            *(half8*)&Kl[row][d0 + 8] = h1;
        }
        // ---- stage V transposed: thread owns keys {kk,kk+1} x 4 d's x 2 passes
        {
            const int kk = (t & 31) * 2;
            const int db = (t >> 5) * 4;
#pragma unroll
            for (int dd = 0; dd < 2; ++dd) {
                const int d0 = db + 32 * dd;
                const float* vp = vbp + (size_t)(kt * KB + kk) * DH + d0;
                f32x4 r0 = *(const f32x4*)(vp);
                f32x4 r1 = *(const f32x4*)(vp + DH);
#pragma unroll
                for (int i = 0; i < 4; ++i) {
                    // Vt[d][kk..kk+1] = {V[kk][d], V[kk+1][d]} ; 2-way-free banks
                    *(half2t*)&Vt[d0 + i][kk] = pkrtz(r0[i], r1[i]);
                }
            }
        }
        __syncthreads();

        // ---- QK^T (swapped): st[mt] C-layout: col=q15, row=key 16mt+4g+r
        f32x4 st[4];
#pragma unroll
        for (int mt = 0; mt < 4; ++mt) {
            f32x4 c = f32x4{0.f, 0.f, 0.f, 0.f};
#pragma unroll
            for (int ss = 0; ss < 2; ++ss) {
                half8 a = *(const half8*)&Kl[16 * mt + q15][8 * g + 32 * ss];
                c = __builtin_amdgcn_mfma_f32_16x16x32_f16(a, qf[ss], c, 0, 0, 0);
            }
            st[mt] = c;
        }

        // ---- mask the (only) partial boundary tile
        const int krem = valid - kt * KB;
        if (krem < KB) {
#pragma unroll
            for (int mt = 0; mt < 4; ++mt)
#pragma unroll
                for (int r = 0; r < 4; ++r)
                    if (16 * mt + 4 * g + r >= krem) st[mt][r] = -1e30f;
        }

        // ---- online softmax (scores already in log2 units)
        float tmax = -1e30f;
#pragma unroll
        for (int mt = 0; mt < 4; ++mt)
#pragma unroll
            for (int r = 0; r < 4; ++r) tmax = fmaxf(tmax, st[mt][r]);
        tmax = fmaxf(tmax, __shfl_xor(tmax, 16));
        tmax = fmaxf(tmax, __shfl_xor(tmax, 32));

        const float mn = fmaxf(m, tmax);
        const float sc = __builtin_amdgcn_exp2f(m - mn);

        float p[4][4];
        float ps = 0.f;
#pragma unroll
        for (int mt = 0; mt < 4; ++mt)
#pragma unroll
            for (int r = 0; r < 4; ++r) {
                const float e = __builtin_amdgcn_exp2f(st[mt][r] - mn);
                p[mt][r] = e;
                ps += e;
            }
        ps += __shfl_xor(ps, 16);
        ps += __shfl_xor(ps, 32);
        lsum = lsum * sc + ps;
        m = mn;
#pragma unroll
        for (int mt = 0; mt < 4; ++mt) acc[mt] *= sc;

        // ---- pack P to f16 (stays in registers; key id carried by slot order)
        half2t pk[4][2];
#pragma unroll
        for (int mt = 0; mt < 4; ++mt)
#pragma unroll
            for (int rr = 0; rr < 2; ++rr)
                pk[mt][rr] = pkrtz(p[mt][2 * rr], p[mt][2 * rr + 1]);

        // ---- PV: out^T += Vt * P^T. B-slot (g,j) carries key 32ss+16(j>>2)+4g+(j&3);
        //      A (Vt) is read in exactly that key order -> slot-consistent, no shuffles.
#pragma unroll
        for (int ss = 0; ss < 2; ++ss) {
            union { half2t h2[4]; half8 v; } bf;
            bf.h2[0] = pk[2 * ss][0];
            bf.h2[1] = pk[2 * ss][1];
            bf.h2[2] = pk[2 * ss + 1][0];
            bf.h2[3] = pk[2 * ss + 1][1];
#pragma unroll
            for (int mt = 0; mt < 4; ++mt) {
                union { half4 h4[2]; half8 v; } af;
                af.h4[0] = *(const half4*)&Vt[16 * mt + q15][32 * ss + 4 * g];
                af.h4[1] = *(const half4*)&Vt[16 * mt + q15][32 * ss + 16 + 4 * g];
                acc[mt] = __builtin_amdgcn_mfma_f32_16x16x32_f16(af.v, bf.v, acc[mt], 0, 0, 0);
            }
        }
    }

    if (!split) {
        // ---- epilogue: divide by softmax denom, store float4 per d-tile
        const float inv = 1.0f / lsum;
        float* op = og + ((size_t)b * SLQ + qrow) * DH;
#pragma unroll
        for (int mt = 0; mt < 4; ++mt) {
            f32x4 o;
#pragma unroll
            for (int r = 0; r < 4; ++r) o[r] = acc[mt][r] * inv;
            *(f32x4*)(op + 16 * mt + 4 * g) = o;
        }
    } else {
        // ---- split epilogue: store unnormalized acc + (m, l) to workspace
        const size_t row = (size_t)b * SLQ + qrow;
        float* wp = ws_acc + ((size_t)s * NB * SLQ + row) * DH;
#pragma unroll
        for (int mt = 0; mt < 4; ++mt)
            *(f32x4*)(wp + 16 * mt + 4 * g) = acc[mt];
        if (g == 0) {
            float2 ml = make_float2(m, lsum);
            *(float2*)(ws_ml + ((size_t)s * NB * SLQ + row) * 2) = ml;
        }
    }
}

__global__ __launch_bounds__(256)
void attn_combine(const float* __restrict__ ws_acc, const float* __restrict__ ws_ml,
                  const int* __restrict__ vn, float* __restrict__ og)
{
    const int tid = blockIdx.x * 256 + threadIdx.x;
    const int row = tid >> 2;            // global q-row 0..32767
    const int dq  = (tid & 3) << 4;      // 16-d chunk
    const int b   = row >> 11;

    const int valid = vn[b];
    const int nkt   = (valid + KB - 1) / KB;
    const int nact  = min(NSPLIT, (nkt + TPS - 1) / TPS);

    float M = -1e30f;
    for (int s = 0; s < nact; ++s)
        M = fmaxf(M, ws_ml[((size_t)s * NB * SLQ + row) * 2]);

    float L = 0.f;
    f32x4 o[4];
#pragma unroll
    for (int i = 0; i < 4; ++i) o[i] = f32x4{0.f, 0.f, 0.f, 0.f};

    for (int s = 0; s < nact; ++s) {
        const float2 ml = *(const float2*)(ws_ml + ((size_t)s * NB * SLQ + row) * 2);
        const float wgt = __builtin_amdgcn_exp2f(ml.x - M);   // m in log2 units
        L += ml.y * wgt;
        const float* ap = ws_acc + ((size_t)s * NB * SLQ + row) * DH + dq;
#pragma unroll
        for (int i = 0; i < 4; ++i) {
            f32x4 a = *(const f32x4*)(ap + 4 * i);
            o[i] += wgt * a;
        }
    }

    const float inv = 1.0f / L;
    float* op = og + (size_t)row * DH + dq;
#pragma unroll
    for (int i = 0; i < 4; ++i) {
        f32x4 r = o[i] * inv;
        *(f32x4*)(op + 4 * i) = r;
    }
}

} // namespace

extern "C" void kernel_launch(void* const* d_in, const int* in_sizes, int n_in,
                              void* d_out, int out_size, void* d_ws, size_t ws_size,
                              hipStream_t stream)
{
    const float* q    = (const float*)d_in[0];
    const float* k    = (const float*)d_in[1];
    const float* v    = (const float*)d_in[2];
    const int*   vnum = (const int*)d_in[3];
    float* out = (float*)d_out;

    const size_t acc_elems = (size_t)NSPLIT * NB * SLQ * DH;     // 8.39M floats
    const size_t ml_elems  = (size_t)NSPLIT * NB * SLQ * 2;
    const size_t need      = (acc_elems + ml_elems) * sizeof(float);  // ~34.6 MB

    float* ws_acc = (float*)d_ws;
    float* ws_ml  = (float*)d_ws + acc_elems;

    if (ws_size >= need) {
        dim3 grid(NSPLIT * NB * (SLQ / QB));   // 2048 blocks
        attn_fwd<<<grid, dim3(256), 0, stream>>>(q, k, v, vnum, out, ws_acc, ws_ml, 1);
        attn_combine<<<dim3((NB * SLQ * 4) / 256), dim3(256), 0, stream>>>(ws_acc, ws_ml, vnum, out);
    } else {
        dim3 grid(NB * (SLQ / QB));            // 512 blocks, fallback
        attn_fwd<<<grid, dim3(256), 0, stream>>>(q, k, v, vnum, out, ws_acc, ws_ml, 0);
    }
}

// Round 5
// 45.801 us; speedup vs baseline: 1.6773x; 1.4980x over previous
//
#include <hip/hip_runtime.h>

// Flash attention fwd, fp32 in/out, f16 MFMA compute, per-batch key masking.
// B=16, LQ=LK=2048, D=64. Swapped QK^T (S^T = K*Q) so softmax is lane-local;
// PV consumes P directly from S^T C-layout registers (slot-consistent with a
// matching Vt LDS read order) -> zero cross-lane shuffles in the main loop.
//
// R2: split-K (NSPLIT=4) + combine kernel.
// R4: drop (256,8) launch-bounds hint (VGPR 56->32 spill regression).
// R5: (a) one-shot prepass converts K->f16 [k][d] and V->f16 transposed [d][k]
//         (kills the per-tile convert+scatter VALU that bound straggler CUs);
//     (b) s-diverse block mapping: co-resident blocks {bid+256k} now span all
//         4 splits and 8 batches (worst-CU 64 -> ~40 tiles);
//     (c) LDS 16KB with XOR swizzle (col^=(row&7)<<3 halves) instead of pads;
//     (d) ws_acc stored normalized f16 (ws total 25.8MB).

namespace {

constexpr int NB  = 16;
constexpr int SLQ = 2048;
constexpr int SLK = 2048;
constexpr int DH  = 64;
constexpr int KB  = 64;   // key tile
constexpr int QB  = 64;   // q rows per block (4 waves x 16)

typedef _Float16 half8  __attribute__((ext_vector_type(8)));
typedef _Float16 half4  __attribute__((ext_vector_type(4)));
typedef _Float16 half2t __attribute__((ext_vector_type(2)));
typedef float    f32x4  __attribute__((ext_vector_type(4)));

__device__ inline half2t pkrtz(float a, float b) {
    return __builtin_bit_cast(half2t, __builtin_amdgcn_cvt_pkrtz(a, b));
}

// ---------------- prepass: K f32->f16 linear; V f32->f16 transposed ----------
__global__ __launch_bounds__(256)
void prepass(const float* __restrict__ kg, const float* __restrict__ vg,
             _Float16* __restrict__ k16, _Float16* __restrict__ v16t)
{
    __shared__ _Float16 VT[DH][72];   // padded transpose staging
    const int t  = threadIdx.x;
    const int b  = blockIdx.x >> 5;
    const int kt = blockIdx.x & 31;

    // K: straight convert, thread covers 16 f32 at tile offset t*16
    {
        const size_t base = ((size_t)b * SLK + (size_t)kt * KB) * DH;
        const float* kp = kg + base + t * 16;
        f32x4 a0 = ((const f32x4*)kp)[0], a1 = ((const f32x4*)kp)[1];
        f32x4 a2 = ((const f32x4*)kp)[2], a3 = ((const f32x4*)kp)[3];
        union { half2t h2[8]; uint4 u[2]; } o;
        o.h2[0] = pkrtz(a0[0], a0[1]); o.h2[1] = pkrtz(a0[2], a0[3]);
        o.h2[2] = pkrtz(a1[0], a1[1]); o.h2[3] = pkrtz(a1[2], a1[3]);
        o.h2[4] = pkrtz(a2[0], a2[1]); o.h2[5] = pkrtz(a2[2], a2[3]);
        o.h2[6] = pkrtz(a3[0], a3[1]); o.h2[7] = pkrtz(a3[2], a3[3]);
        uint4* dst = (uint4*)(k16 + base + t * 16);
        dst[0] = o.u[0]; dst[1] = o.u[1];
    }
    // V: transpose via LDS (cheap here: once per (b,kt), not per q-block/split)
    {
        const int kr = t >> 2, d0 = (t & 3) * 16;
        const float* vp = vg + ((size_t)b * SLK + (size_t)kt * KB + kr) * DH + d0;
        f32x4 a0 = ((const f32x4*)vp)[0], a1 = ((const f32x4*)vp)[1];
        f32x4 a2 = ((const f32x4*)vp)[2], a3 = ((const f32x4*)vp)[3];
#pragma unroll
        for (int i = 0; i < 4; ++i) {
            VT[d0 + i][kr]      = (_Float16)a0[i];
            VT[d0 + 4 + i][kr]  = (_Float16)a1[i];
            VT[d0 + 8 + i][kr]  = (_Float16)a2[i];
            VT[d0 + 12 + i][kr] = (_Float16)a3[i];
        }
    }
    __syncthreads();
#pragma unroll
    for (int j = 0; j < 2; ++j) {
        const int chunk = t * 2 + j;
        const int d = chunk >> 3, c16 = chunk & 7;
        half8 hv = *(const half8*)&VT[d][c16 * 8];
        *(half8*)(v16t + ((size_t)b * DH + d) * SLK + (size_t)kt * KB + c16 * 8) = hv;
    }
}

// ---------------- main flash kernel (split-K, writes normalized f16 acc) -----
__global__ __launch_bounds__(256)
void attn_fwd(const float* __restrict__ qg, const _Float16* __restrict__ k16,
              const _Float16* __restrict__ v16t, const int* __restrict__ vn,
              _Float16* __restrict__ ws_acc, float* __restrict__ ws_ml,
              int nsplit, int tps)
{
    __shared__ _Float16 Kl[KB * DH];   // [key][d] rows 64h, XOR-swizzled cols
    __shared__ _Float16 Vt[DH * KB];   // [d][key] rows 64h, XOR-swizzled cols

    const int t   = threadIdx.x;
    const int l   = t & 63;
    const int w   = t >> 6;     // wave id 0..3
    const int q15 = l & 15;     // q col within wave's 16 rows (C-layout col)
    const int g   = l >> 4;     // lane group 0..3
    const int swz = (q15 & 7) << 3;

    const int bid = blockIdx.x;
    int b, qt, s;
    if (nsplit == 4) {
        // co-resident blocks {bid+256k} get s=k&3 (all splits), b=(m+k)&15
        const int k3  = bid >> 8;           // 0..7
        const int mm  = (bid >> 4) & 15;
        const int qlo = bid & 15;
        s  = k3 & 3;
        b  = (mm + k3) & 15;
        qt = qlo | ((k3 >> 2) << 4);
    } else {
        b  = ((bid & 15) + 8 * (bid >> 8)) & 15;
        qt = (bid >> 4) & 31;
        s  = 0;
    }

    const int valid = vn[b];
    const int nkt   = (valid + KB - 1) / KB;
    const int kt0   = s * tps;
    if (kt0 >= nkt) return;                  // wave-uniform early out
    const int kt1   = min(nkt, kt0 + tps);

    const int qrow = qt * QB + w * 16 + q15;

    // fold 1/sqrt(D)=1/8 and log2(e) into Q: scores land in log2 units
    const float QS = 0.18033688011112042f;

    half8 qf[2];
    {
        const float* qp = qg + ((size_t)b * SLQ + qrow) * DH;
#pragma unroll
        for (int ss = 0; ss < 2; ++ss) {
            const int d0 = 8 * g + 32 * ss;
            f32x4 x = *(const f32x4*)(qp + d0);
            f32x4 y = *(const f32x4*)(qp + d0 + 4);
            half8 h;
#pragma unroll
            for (int i = 0; i < 4; ++i) {
                h[i]     = (_Float16)(x[i] * QS);
                h[i + 4] = (_Float16)(y[i] * QS);
            }
            qf[ss] = h;
        }
    }

    f32x4 acc[4];
#pragma unroll
    for (int i = 0; i < 4; ++i) acc[i] = f32x4{0.f, 0.f, 0.f, 0.f};
    float m = -1e30f, lsum = 0.f;

    const _Float16* k16b = k16 + (size_t)b * SLK * DH;
    const _Float16* v16b = v16t + (size_t)b * DH * SLK;

    for (int kt = kt0; kt < kt1; ++kt) {
        __syncthreads();   // previous tile's reads done before overwrite

        // ---- stage: pure b128 copies, swizzled LDS writes, zero converts
#pragma unroll
        for (int j = 0; j < 2; ++j) {
            const int chunk = 2 * t + j;          // 0..511
            const int r = chunk >> 3, c16 = chunk & 7;
            const int sc = (c16 * 8) ^ ((r & 7) << 3);
            uint4 kd = *(const uint4*)(k16b + (size_t)kt * KB * DH + chunk * 8);
            *(uint4*)&Kl[r * 64 + sc] = kd;
            uint4 vd = *(const uint4*)(v16b + (size_t)r * SLK + kt * KB + c16 * 8);
            *(uint4*)&Vt[r * 64 + sc] = vd;
        }
        __syncthreads();

        // ---- QK^T (swapped): st[mt] C-layout: col=q15, row=key 16mt+4g+r
        f32x4 st[4];
#pragma unroll
        for (int mt = 0; mt < 4; ++mt) {
            f32x4 c = f32x4{0.f, 0.f, 0.f, 0.f};
#pragma unroll
            for (int ss = 0; ss < 2; ++ss) {
                half8 a = *(const half8*)&Kl[(16 * mt + q15) * 64 + ((8 * g + 32 * ss) ^ swz)];
                c = __builtin_amdgcn_mfma_f32_16x16x32_f16(a, qf[ss], c, 0, 0, 0);
            }
            st[mt] = c;
        }

        // ---- mask the (only) partial boundary tile
        const int krem = valid - kt * KB;
        if (krem < KB) {
#pragma unroll
            for (int mt = 0; mt < 4; ++mt)
#pragma unroll
                for (int r = 0; r < 4; ++r)
                    if (16 * mt + 4 * g + r >= krem) st[mt][r] = -1e30f;
        }

        // ---- online softmax (log2 units)
        float tmax = -1e30f;
#pragma unroll
        for (int mt = 0; mt < 4; ++mt)
#pragma unroll
            for (int r = 0; r < 4; ++r) tmax = fmaxf(tmax, st[mt][r]);
        tmax = fmaxf(tmax, __shfl_xor(tmax, 16));
        tmax = fmaxf(tmax, __shfl_xor(tmax, 32));

        const float mn = fmaxf(m, tmax);
        const float sc = __builtin_amdgcn_exp2f(m - mn);

        float p[4][4];
        float ps = 0.f;
#pragma unroll
        for (int mt = 0; mt < 4; ++mt)
#pragma unroll
            for (int r = 0; r < 4; ++r) {
                const float e = __builtin_amdgcn_exp2f(st[mt][r] - mn);
                p[mt][r] = e;
                ps += e;
            }
        ps += __shfl_xor(ps, 16);
        ps += __shfl_xor(ps, 32);
        lsum = lsum * sc + ps;
        m = mn;
#pragma unroll
        for (int mt = 0; mt < 4; ++mt) acc[mt] *= sc;

        half2t pk[4][2];
#pragma unroll
        for (int mt = 0; mt < 4; ++mt)
#pragma unroll
            for (int rr = 0; rr < 2; ++rr)
                pk[mt][rr] = pkrtz(p[mt][2 * rr], p[mt][2 * rr + 1]);

        // ---- PV: out^T += Vt * P^T (slot-consistent, no shuffles)
#pragma unroll
        for (int ss = 0; ss < 2; ++ss) {
            union { half2t h2[4]; half8 v; } bf;
            bf.h2[0] = pk[2 * ss][0];
            bf.h2[1] = pk[2 * ss][1];
            bf.h2[2] = pk[2 * ss + 1][0];
            bf.h2[3] = pk[2 * ss + 1][1];
#pragma unroll
            for (int mt = 0; mt < 4; ++mt) {
                union { half4 h4[2]; half8 v; } af;
                af.h4[0] = *(const half4*)&Vt[(16 * mt + q15) * 64 + ((32 * ss + 4 * g) ^ swz)];
                af.h4[1] = *(const half4*)&Vt[(16 * mt + q15) * 64 + ((32 * ss + 16 + 4 * g) ^ swz)];
                acc[mt] = __builtin_amdgcn_mfma_f32_16x16x32_f16(af.v, bf.v, acc[mt], 0, 0, 0);
            }
        }
    }

    // ---- epilogue: normalized f16 acc + (m,l) to workspace
    const float inv = 1.0f / lsum;
    const size_t row = (size_t)b * SLQ + qrow;
    _Float16* wp = ws_acc + ((size_t)s * NB * SLQ + row) * DH;
#pragma unroll
    for (int mt = 0; mt < 4; ++mt) {
        union { half2t h2[2]; uint2 u; } o;
        o.h2[0] = pkrtz(acc[mt][0] * inv, acc[mt][1] * inv);
        o.h2[1] = pkrtz(acc[mt][2] * inv, acc[mt][3] * inv);
        *(uint2*)(wp + 16 * mt + 4 * g) = o.u;
    }
    if (g == 0)
        *(float2*)(ws_ml + ((size_t)s * NB * SLQ + row) * 2) = make_float2(m, lsum);
}

// ---------------- combine ----------------------------------------------------
__global__ __launch_bounds__(256)
void attn_combine(const _Float16* __restrict__ ws_acc, const float* __restrict__ ws_ml,
                  const int* __restrict__ vn, float* __restrict__ og,
                  int nsplit, int tps)
{
    const int tid = blockIdx.x * 256 + threadIdx.x;
    const int row = tid >> 2;
    const int dq  = (tid & 3) << 4;
    const int b   = row >> 11;

    const int valid = vn[b];
    const int nkt   = (valid + KB - 1) / KB;
    const int nact  = min(nsplit, (nkt + tps - 1) / tps);

    float M = -1e30f;
    for (int s = 0; s < nact; ++s)
        M = fmaxf(M, ws_ml[((size_t)s * NB * SLQ + row) * 2]);

    float L = 0.f;
    f32x4 o[4];
#pragma unroll
    for (int i = 0; i < 4; ++i) o[i] = f32x4{0.f, 0.f, 0.f, 0.f};

    for (int s = 0; s < nact; ++s) {
        const float2 ml = *(const float2*)(ws_ml + ((size_t)s * NB * SLQ + row) * 2);
        const float wl = __builtin_amdgcn_exp2f(ml.x - M) * ml.y;  // weight * l_s
        L += wl;
        const _Float16* ap = ws_acc + ((size_t)s * NB * SLQ + row) * DH + dq;
        half8 h0 = ((const half8*)ap)[0];
        half8 h1 = ((const half8*)ap)[1];
#pragma unroll
        for (int r = 0; r < 4; ++r) {
            o[0][r] += wl * (float)h0[r];
            o[1][r] += wl * (float)h0[4 + r];
            o[2][r] += wl * (float)h1[r];
            o[3][r] += wl * (float)h1[4 + r];
        }
    }

    const float inv = 1.0f / L;
    float* op = og + (size_t)row * DH + dq;
#pragma unroll
    for (int i = 0; i < 4; ++i) {
        f32x4 r = o[i] * inv;
        *(f32x4*)(op + 4 * i) = r;
    }
}

} // namespace

extern "C" void kernel_launch(void* const* d_in, const int* in_sizes, int n_in,
                              void* d_out, int out_size, void* d_ws, size_t ws_size,
                              hipStream_t stream)
{
    const float* q    = (const float*)d_in[0];
    const float* k    = (const float*)d_in[1];
    const float* v    = (const float*)d_in[2];
    const int*   vnum = (const int*)d_in[3];
    float* out = (float*)d_out;

    const size_t k16H = (size_t)NB * SLK * DH;          // 2.10M halves (4 MB)
    const size_t v16H = k16H;
    const size_t rowsH = (size_t)NB * SLQ;              // 32768 q-rows

    // choose split count by workspace budget
    int nsplit = 4;
    {
        const size_t need4 = (k16H + v16H + 4 * rowsH * DH) * 2 + 4 * rowsH * 2 * 4;
        if (ws_size < need4) nsplit = 1;                // 12.5 MB fallback
    }
    const int tps = (nsplit == 4) ? 8 : 32;

    _Float16* k16    = (_Float16*)d_ws;
    _Float16* v16t   = k16 + k16H;
    _Float16* ws_acc = v16t + v16H;
    float*    ws_ml  = (float*)(ws_acc + (size_t)nsplit * rowsH * DH);

    prepass<<<dim3(NB * (SLK / KB)), dim3(256), 0, stream>>>(k, v, k16, v16t);

    dim3 gfwd(nsplit == 4 ? 2048 : 512);
    attn_fwd<<<gfwd, dim3(256), 0, stream>>>(q, k16, v16t, vnum, ws_acc, ws_ml,
                                             nsplit, tps);

    attn_combine<<<dim3((NB * SLQ * 4) / 256), dim3(256), 0, stream>>>(
        ws_acc, ws_ml, vnum, out, nsplit, tps);
}

// Round 6
// 43.868 us; speedup vs baseline: 1.7512x; 1.0441x over previous
//
#include <hip/hip_runtime.h>

// Flash attention fwd, fp32 in/out, f16 MFMA compute, per-batch key masking.
// B=16, LQ=LK=2048, D=64. Swapped QK^T (S^T = K*Q) so softmax is lane-local;
// PV consumes P directly from S^T C-layout registers (slot-consistent with a
// matching Vt LDS read order) -> zero cross-lane shuffles in the main loop.
//
// R2: split-K + combine kernel.
// R4: drop (256,8) launch-bounds hint (VGPR 56->32 spill regression).
// R5: prepass K/V -> f16 (V transposed); XOR-swizzled 16KB LDS; f16 ws_acc.
// R6: (a) T14 prefetch: tile t+1 global->regs issued during tile t compute;
//     (b) NSPLIT 4->8 (TPS=4, 4096 blocks) + s/b/qt-diverse bijective map
//         -> deeper per-CU queue, dynamic balance;
//     (c) pairwise max/sum trees, T13 defer-max (thr 12 in log2 units),
//         T5 setprio around MFMA clusters.

namespace {

constexpr int NB  = 16;
constexpr int SLQ = 2048;
constexpr int SLK = 2048;
constexpr int DH  = 64;
constexpr int KB  = 64;   // key tile
constexpr int QB  = 64;   // q rows per block (4 waves x 16)

typedef _Float16 half8  __attribute__((ext_vector_type(8)));
typedef _Float16 half4  __attribute__((ext_vector_type(4)));
typedef _Float16 half2t __attribute__((ext_vector_type(2)));
typedef float    f32x4  __attribute__((ext_vector_type(4)));

__device__ inline half2t pkrtz(float a, float b) {
    return __builtin_bit_cast(half2t, __builtin_amdgcn_cvt_pkrtz(a, b));
}

// ---------------- prepass: K f32->f16 linear; V f32->f16 transposed ----------
__global__ __launch_bounds__(256)
void prepass(const float* __restrict__ kg, const float* __restrict__ vg,
             _Float16* __restrict__ k16, _Float16* __restrict__ v16t)
{
    __shared__ _Float16 VT[DH][72];   // padded transpose staging
    const int t  = threadIdx.x;
    const int b  = blockIdx.x >> 5;
    const int kt = blockIdx.x & 31;

    // K: straight convert, thread covers 16 f32 at tile offset t*16
    {
        const size_t base = ((size_t)b * SLK + (size_t)kt * KB) * DH;
        const float* kp = kg + base + t * 16;
        f32x4 a0 = ((const f32x4*)kp)[0], a1 = ((const f32x4*)kp)[1];
        f32x4 a2 = ((const f32x4*)kp)[2], a3 = ((const f32x4*)kp)[3];
        union { half2t h2[8]; uint4 u[2]; } o;
        o.h2[0] = pkrtz(a0[0], a0[1]); o.h2[1] = pkrtz(a0[2], a0[3]);
        o.h2[2] = pkrtz(a1[0], a1[1]); o.h2[3] = pkrtz(a1[2], a1[3]);
        o.h2[4] = pkrtz(a2[0], a2[1]); o.h2[5] = pkrtz(a2[2], a2[3]);
        o.h2[6] = pkrtz(a3[0], a3[1]); o.h2[7] = pkrtz(a3[2], a3[3]);
        uint4* dst = (uint4*)(k16 + base + t * 16);
        dst[0] = o.u[0]; dst[1] = o.u[1];
    }
    // V: transpose via LDS (once per (b,kt), not per q-block/split)
    {
        const int kr = t >> 2, d0 = (t & 3) * 16;
        const float* vp = vg + ((size_t)b * SLK + (size_t)kt * KB + kr) * DH + d0;
        f32x4 a0 = ((const f32x4*)vp)[0], a1 = ((const f32x4*)vp)[1];
        f32x4 a2 = ((const f32x4*)vp)[2], a3 = ((const f32x4*)vp)[3];
#pragma unroll
        for (int i = 0; i < 4; ++i) {
            VT[d0 + i][kr]      = (_Float16)a0[i];
            VT[d0 + 4 + i][kr]  = (_Float16)a1[i];
            VT[d0 + 8 + i][kr]  = (_Float16)a2[i];
            VT[d0 + 12 + i][kr] = (_Float16)a3[i];
        }
    }
    __syncthreads();
#pragma unroll
    for (int j = 0; j < 2; ++j) {
        const int chunk = t * 2 + j;
        const int d = chunk >> 3, c16 = chunk & 7;
        half8 hv = *(const half8*)&VT[d][c16 * 8];
        *(half8*)(v16t + ((size_t)b * DH + d) * SLK + (size_t)kt * KB + c16 * 8) = hv;
    }
}

// ---------------- main flash kernel (split-K, writes normalized f16 acc) -----
__global__ __launch_bounds__(256)
void attn_fwd(const float* __restrict__ qg, const _Float16* __restrict__ k16,
              const _Float16* __restrict__ v16t, const int* __restrict__ vn,
              _Float16* __restrict__ ws_acc, float* __restrict__ ws_ml,
              int nsplit, int tps)
{
    __shared__ _Float16 Kl[KB * DH];   // [key][d] rows 64h, XOR-swizzled cols
    __shared__ _Float16 Vt[DH * KB];   // [d][key] rows 64h, XOR-swizzled cols

    const int t   = threadIdx.x;
    const int l   = t & 63;
    const int w   = t >> 6;     // wave id 0..3
    const int q15 = l & 15;     // q col within wave's 16 rows (C-layout col)
    const int g   = l >> 4;     // lane group 0..3
    const int swz = (q15 & 7) << 3;

    const int bid = blockIdx.x;
    int b, qt, s;
    if (nsplit == 8) {
        // co-resident blocks {bid+256k}: s=k&7 (all splits), b=(m+k)&15
        const int k4 = bid >> 8;            // 0..15
        s  = k4 & 7;
        b  = (((bid >> 4) & 15) + k4) & 15;
        qt = (bid & 15) | ((k4 >> 3) << 4);
    } else {
        b  = ((bid & 15) + 8 * (bid >> 8)) & 15;
        qt = (bid >> 4) & 31;
        s  = 0;
    }

    const int valid = vn[b];
    const int nkt   = (valid + KB - 1) / KB;
    const int kt0   = s * tps;
    if (kt0 >= nkt) return;                  // block-uniform early out
    const int kt1   = min(nkt, kt0 + tps);

    const int qrow = qt * QB + w * 16 + q15;

    // fold 1/sqrt(D)=1/8 and log2(e) into Q: scores land in log2 units
    const float QS = 0.18033688011112042f;

    half8 qf[2];
    {
        const float* qp = qg + ((size_t)b * SLQ + qrow) * DH;
#pragma unroll
        for (int ss = 0; ss < 2; ++ss) {
            const int d0 = 8 * g + 32 * ss;
            f32x4 x = *(const f32x4*)(qp + d0);
            f32x4 y = *(const f32x4*)(qp + d0 + 4);
            half8 h;
#pragma unroll
            for (int i = 0; i < 4; ++i) {
                h[i]     = (_Float16)(x[i] * QS);
                h[i + 4] = (_Float16)(y[i] * QS);
            }
            qf[ss] = h;
        }
    }

    f32x4 acc[4];
#pragma unroll
    for (int i = 0; i < 4; ++i) acc[i] = f32x4{0.f, 0.f, 0.f, 0.f};
    float m = -1e30f, lsum = 0.f;

    const _Float16* k16b = k16 + (size_t)b * SLK * DH;
    const _Float16* v16b = v16t + (size_t)b * DH * SLK;

    // per-thread stage addressing (constant over tiles)
    const int chunk = 2 * t;                 // even, 0..510
    const int rr_   = chunk >> 3;            // row 0..63
    const int cc_   = chunk & 7;             // even col-chunk
    const int scA   = (cc_ * 8) ^ ((rr_ & 7) << 3);
    const int scB   = scA ^ 8;
    const _Float16* ksrc = k16b + (size_t)chunk * 8;
    const _Float16* vsrc = v16b + (size_t)rr_ * SLK + cc_ * 8;

    uint4 ka, kb, va, vb;
#define PREFETCH(KT)                                                       \
    {                                                                      \
        const _Float16* kp = ksrc + (size_t)(KT) * (KB * DH);              \
        ka = ((const uint4*)kp)[0];                                        \
        kb = ((const uint4*)kp)[1];                                        \
        const _Float16* vp = vsrc + (size_t)(KT) * KB;                     \
        va = ((const uint4*)vp)[0];                                        \
        vb = ((const uint4*)vp)[1];                                        \
    }

    PREFETCH(kt0);

    for (int kt = kt0; kt < kt1; ++kt) {
        __syncthreads();   // previous tile's LDS reads done before overwrite

        // ---- write prefetched tile to LDS (swizzled), then prefetch next
        *(uint4*)&Kl[rr_ * 64 + scA] = ka;
        *(uint4*)&Kl[rr_ * 64 + scB] = kb;
        *(uint4*)&Vt[rr_ * 64 + scA] = va;
        *(uint4*)&Vt[rr_ * 64 + scB] = vb;
        if (kt + 1 < kt1) PREFETCH(kt + 1);   // latency hides under compute
        __syncthreads();

        // ---- QK^T (swapped): st[mt] C-layout: col=q15, row=key 16mt+4g+r
        f32x4 st[4];
        __builtin_amdgcn_s_setprio(1);
#pragma unroll
        for (int mt = 0; mt < 4; ++mt) {
            f32x4 c = f32x4{0.f, 0.f, 0.f, 0.f};
#pragma unroll
            for (int ss = 0; ss < 2; ++ss) {
                half8 a = *(const half8*)&Kl[(16 * mt + q15) * 64 + ((8 * g + 32 * ss) ^ swz)];
                c = __builtin_amdgcn_mfma_f32_16x16x32_f16(a, qf[ss], c, 0, 0, 0);
            }
            st[mt] = c;
        }
        __builtin_amdgcn_s_setprio(0);

        // ---- mask the (only) partial boundary tile
        const int krem = valid - kt * KB;
        if (krem < KB) {
#pragma unroll
            for (int mt = 0; mt < 4; ++mt)
#pragma unroll
                for (int r = 0; r < 4; ++r)
                    if (16 * mt + 4 * g + r >= krem) st[mt][r] = -1e30f;
        }

        // ---- tile max: pairwise tree (short dep chain)
        float x0 = fmaxf(fmaxf(st[0][0], st[0][1]), fmaxf(st[0][2], st[0][3]));
        float x1 = fmaxf(fmaxf(st[1][0], st[1][1]), fmaxf(st[1][2], st[1][3]));
        float x2 = fmaxf(fmaxf(st[2][0], st[2][1]), fmaxf(st[2][2], st[2][3]));
        float x3 = fmaxf(fmaxf(st[3][0], st[3][1]), fmaxf(st[3][2], st[3][3]));
        float tmax = fmaxf(fmaxf(x0, x1), fmaxf(x2, x3));
        tmax = fmaxf(tmax, __shfl_xor(tmax, 16));
        tmax = fmaxf(tmax, __shfl_xor(tmax, 32));

        // ---- T13 defer-max: skip rescale while growth <= 12 (P <= 2^12, f16-safe)
        if (!__all(tmax - m <= 12.0f)) {
            const float mn = fmaxf(m, tmax);
            const float sc = __builtin_amdgcn_exp2f(m - mn);
            lsum *= sc;
#pragma unroll
            for (int mt = 0; mt < 4; ++mt) acc[mt] *= sc;
            m = mn;
        }

        float p[4][4];
#pragma unroll
        for (int mt = 0; mt < 4; ++mt)
#pragma unroll
            for (int r = 0; r < 4; ++r)
                p[mt][r] = __builtin_amdgcn_exp2f(st[mt][r] - m);

        // pairwise sum tree
        float s0 = (p[0][0] + p[0][1]) + (p[0][2] + p[0][3]);
        float s1 = (p[1][0] + p[1][1]) + (p[1][2] + p[1][3]);
        float s2 = (p[2][0] + p[2][1]) + (p[2][2] + p[2][3]);
        float s3 = (p[3][0] + p[3][1]) + (p[3][2] + p[3][3]);
        float ps = (s0 + s1) + (s2 + s3);
        ps += __shfl_xor(ps, 16);
        ps += __shfl_xor(ps, 32);
        lsum += ps;

        half2t pk[4][2];
#pragma unroll
        for (int mt = 0; mt < 4; ++mt)
#pragma unroll
            for (int rr = 0; rr < 2; ++rr)
                pk[mt][rr] = pkrtz(p[mt][2 * rr], p[mt][2 * rr + 1]);

        // ---- PV: out^T += Vt * P^T (slot-consistent, no shuffles)
        __builtin_amdgcn_s_setprio(1);
#pragma unroll
        for (int ss = 0; ss < 2; ++ss) {
            union { half2t h2[4]; half8 v; } bf;
            bf.h2[0] = pk[2 * ss][0];
            bf.h2[1] = pk[2 * ss][1];
            bf.h2[2] = pk[2 * ss + 1][0];
            bf.h2[3] = pk[2 * ss + 1][1];
#pragma unroll
            for (int mt = 0; mt < 4; ++mt) {
                union { half4 h4[2]; half8 v; } af;
                af.h4[0] = *(const half4*)&Vt[(16 * mt + q15) * 64 + ((32 * ss + 4 * g) ^ swz)];
                af.h4[1] = *(const half4*)&Vt[(16 * mt + q15) * 64 + ((32 * ss + 16 + 4 * g) ^ swz)];
                acc[mt] = __builtin_amdgcn_mfma_f32_16x16x32_f16(af.v, bf.v, acc[mt], 0, 0, 0);
            }
        }
        __builtin_amdgcn_s_setprio(0);
    }
#undef PREFETCH

    // ---- epilogue: normalized f16 acc + (m,l) to workspace
    const float inv = 1.0f / lsum;
    const size_t row = (size_t)b * SLQ + qrow;
    _Float16* wp = ws_acc + ((size_t)s * NB * SLQ + row) * DH;
#pragma unroll
    for (int mt = 0; mt < 4; ++mt) {
        union { half2t h2[2]; uint2 u; } o;
        o.h2[0] = pkrtz(acc[mt][0] * inv, acc[mt][1] * inv);
        o.h2[1] = pkrtz(acc[mt][2] * inv, acc[mt][3] * inv);
        *(uint2*)(wp + 16 * mt + 4 * g) = o.u;
    }
    if (g == 0)
        *(float2*)(ws_ml + ((size_t)s * NB * SLQ + row) * 2) = make_float2(m, lsum);
}

// ---------------- combine ----------------------------------------------------
__global__ __launch_bounds__(256)
void attn_combine(const _Float16* __restrict__ ws_acc, const float* __restrict__ ws_ml,
                  const int* __restrict__ vn, float* __restrict__ og,
                  int nsplit, int tps)
{
    const int tid = blockIdx.x * 256 + threadIdx.x;
    const int row = tid >> 2;
    const int dq  = (tid & 3) << 4;
    const int b   = row >> 11;

    const int valid = vn[b];
    const int nkt   = (valid + KB - 1) / KB;
    const int nact  = min(nsplit, (nkt + tps - 1) / tps);

    float M = -1e30f;
    for (int s = 0; s < nact; ++s)
        M = fmaxf(M, ws_ml[((size_t)s * NB * SLQ + row) * 2]);

    float L = 0.f;
    f32x4 o[4];
#pragma unroll
    for (int i = 0; i < 4; ++i) o[i] = f32x4{0.f, 0.f, 0.f, 0.f};

    for (int s = 0; s < nact; ++s) {
        const float2 ml = *(const float2*)(ws_ml + ((size_t)s * NB * SLQ + row) * 2);
        const float wl = __builtin_amdgcn_exp2f(ml.x - M) * ml.y;  // weight * l_s
        L += wl;
        const _Float16* ap = ws_acc + ((size_t)s * NB * SLQ + row) * DH + dq;
        half8 h0 = ((const half8*)ap)[0];
        half8 h1 = ((const half8*)ap)[1];
#pragma unroll
        for (int r = 0; r < 4; ++r) {
            o[0][r] += wl * (float)h0[r];
            o[1][r] += wl * (float)h0[4 + r];
            o[2][r] += wl * (float)h1[r];
            o[3][r] += wl * (float)h1[4 + r];
        }
    }

    const float inv = 1.0f / L;
    float* op = og + (size_t)row * DH + dq;
#pragma unroll
    for (int i = 0; i < 4; ++i) {
        f32x4 r = o[i] * inv;
        *(f32x4*)(op + 4 * i) = r;
    }
}

} // namespace

extern "C" void kernel_launch(void* const* d_in, const int* in_sizes, int n_in,
                              void* d_out, int out_size, void* d_ws, size_t ws_size,
                              hipStream_t stream)
{
    const float* q    = (const float*)d_in[0];
    const float* k    = (const float*)d_in[1];
    const float* v    = (const float*)d_in[2];
    const int*   vnum = (const int*)d_in[3];
    float* out = (float*)d_out;

    const size_t k16H  = (size_t)NB * SLK * DH;         // 2.10M halves (4 MB)
    const size_t v16H  = k16H;
    const size_t rowsH = (size_t)NB * SLQ;              // 32768 q-rows

    // choose split count by workspace budget (~44 MB for nsplit=8)
    int nsplit = 8;
    {
        const size_t need8 = (k16H + v16H + (size_t)8 * rowsH * DH) * 2
                           + (size_t)8 * rowsH * 2 * 4;
        if (ws_size < need8) nsplit = 1;                // 12.5 MB fallback
    }
    const int tps = (nsplit == 8) ? 4 : 32;

    _Float16* k16    = (_Float16*)d_ws;
    _Float16* v16t   = k16 + k16H;
    _Float16* ws_acc = v16t + v16H;
    float*    ws_ml  = (float*)(ws_acc + (size_t)nsplit * rowsH * DH);

    prepass<<<dim3(NB * (SLK / KB)), dim3(256), 0, stream>>>(k, v, k16, v16t);

    dim3 gfwd(nsplit == 8 ? 4096 : 512);
    attn_fwd<<<gfwd, dim3(256), 0, stream>>>(q, k16, v16t, vnum, ws_acc, ws_ml,
                                             nsplit, tps);

    attn_combine<<<dim3((NB * SLQ * 4) / 256), dim3(256), 0, stream>>>(
        ws_acc, ws_ml, vnum, out, nsplit, tps);
}

// Round 8
// 43.622 us; speedup vs baseline: 1.7611x; 1.0057x over previous
//
#include <hip/hip_runtime.h>

// Flash attention fwd, fp32 in/out, f16 MFMA compute, per-batch key masking.
// B=16, LQ=LK=2048, D=64. Swapped QK^T (S^T = K*Q) so softmax is lane-local;
// PV consumes P directly from S^T C-layout registers (slot-consistent with a
// matching Vt LDS read order) -> zero cross-lane shuffles in the main loop.
//
// R2: split-K + combine kernel.
// R4: drop (256,8) launch-bounds hint (VGPR 56->32 spill regression).
// R5: prepass K/V -> f16 (V transposed); XOR-swizzled LDS; f16 ws_acc.
// R6: reg-prefetch + trees + defer-max + setprio + nsplit=8.
// R7 (FAILED): global_load_lds one-barrier pipeline -> stale tiles. Layout
//     was element-trace-verified correct; the DMA/barrier-drain rotation was
//     the unproven piece.
// R8: one-barrier DOUBLE-BUFFER with register staging (provable semantics):
//     WRITEKV(cur); barrier; LOADREGS(kt+1); compute(cur). Loads never cross
//     a barrier; writes/reads of a buffer always separated by one barrier.
//     Keeps R7's pre-swizzled tile-contiguous workspace (zero staging VALU).

namespace {

constexpr int NB  = 16;
constexpr int SLQ = 2048;
constexpr int SLK = 2048;
constexpr int DH  = 64;
constexpr int KB  = 64;   // key tile
constexpr int QB  = 64;   // q rows per block (4 waves x 16)

typedef _Float16 half8  __attribute__((ext_vector_type(8)));
typedef _Float16 half4  __attribute__((ext_vector_type(4)));
typedef _Float16 half2t __attribute__((ext_vector_type(2)));
typedef float    f32x4  __attribute__((ext_vector_type(4)));

__device__ inline half2t pkrtz(float a, float b) {
    return __builtin_bit_cast(half2t, __builtin_amdgcn_cvt_pkrtz(a, b));
}

// ---------------- prepass -----------------------------------------------
// K tiles: kws[(b*32+kt)*4096 + (rr*8 + (c^(rr&7)))*8 .. +8] = f16(K[b, kt*64+rr, c*8..+8])
// V tiles: vws[(b*32+kt)*4096 + (d*8 + (c^(d&7)))*8 .. +8]  = f16(V[b, kt*64+c*8..+8, d])^T
// i.e. tile-contiguous 8KB with the LDS bank-XOR baked into chunk placement,
// so fwd stages linearly and keeps its swizzled ds_reads.
// (Element-trace verified: K[0,17,35] -> ws chunk 141 half 1131 -> read
//  mt=1,q15=1,ss=1,g=0 offset 1128+3; V[0,17,35] -> ws half 2249 -> read
//  mt=2,q15=3,ss=0 second-half4 g=0 offset 2248+1.)
__global__ __launch_bounds__(256)
void prepass(const float* __restrict__ kg, const float* __restrict__ vg,
             _Float16* __restrict__ kws, _Float16* __restrict__ vws)
{
    __shared__ _Float16 VT[DH][72];   // padded transpose staging
    const int t  = threadIdx.x;
    const int b  = blockIdx.x >> 5;
    const int kt = blockIdx.x & 31;
    const size_t tileH = ((size_t)(b << 5) + kt) * 4096;

    // K: thread covers source chunks n=2t, 2t+1 (8 f32 -> 8 f16 each)
    {
        const float* kp = kg + ((size_t)b * SLK + (size_t)kt * KB) * DH + t * 16;
        f32x4 a0 = ((const f32x4*)kp)[0], a1 = ((const f32x4*)kp)[1];
        f32x4 a2 = ((const f32x4*)kp)[2], a3 = ((const f32x4*)kp)[3];
        union { half2t h2[4]; uint4 u; } o0, o1;
        o0.h2[0] = pkrtz(a0[0], a0[1]); o0.h2[1] = pkrtz(a0[2], a0[3]);
        o0.h2[2] = pkrtz(a1[0], a1[1]); o0.h2[3] = pkrtz(a1[2], a1[3]);
        o1.h2[0] = pkrtz(a2[0], a2[1]); o1.h2[1] = pkrtz(a2[2], a2[3]);
        o1.h2[2] = pkrtz(a3[0], a3[1]); o1.h2[3] = pkrtz(a3[2], a3[3]);
#pragma unroll
        for (int j = 0; j < 2; ++j) {
            const int n = 2 * t + j;
            const int rr = n >> 3, c = n & 7;
            const int dst = rr * 8 + (c ^ (rr & 7));
            *(uint4*)(kws + tileH + (size_t)dst * 8) = j ? o1.u : o0.u;
        }
    }
    // V: transpose via LDS (once per (b,kt))
    {
        const int kr = t >> 2, d0 = (t & 3) * 16;
        const float* vp = vg + ((size_t)b * SLK + (size_t)kt * KB + kr) * DH + d0;
        f32x4 a0 = ((const f32x4*)vp)[0], a1 = ((const f32x4*)vp)[1];
        f32x4 a2 = ((const f32x4*)vp)[2], a3 = ((const f32x4*)vp)[3];
#pragma unroll
        for (int i = 0; i < 4; ++i) {
            VT[d0 + i][kr]      = (_Float16)a0[i];
            VT[d0 + 4 + i][kr]  = (_Float16)a1[i];
            VT[d0 + 8 + i][kr]  = (_Float16)a2[i];
            VT[d0 + 12 + i][kr] = (_Float16)a3[i];
        }
    }
    __syncthreads();
#pragma unroll
    for (int j = 0; j < 2; ++j) {
        const int n = 2 * t + j;
        const int d = n >> 3, c = n & 7;
        const int dst = d * 8 + (c ^ (d & 7));
        half8 hv = *(const half8*)&VT[d][c * 8];
        *(half8*)(vws + tileH + (size_t)dst * 8) = hv;
    }
}

// ---------------- main flash kernel (split-K, writes normalized f16 acc) ----
__global__ __launch_bounds__(256)
void attn_fwd(const float* __restrict__ qg, const _Float16* __restrict__ k16,
              const _Float16* __restrict__ v16, const int* __restrict__ vn,
              _Float16* __restrict__ ws_acc, float* __restrict__ ws_ml,
              int nsplit, int tps)
{
    // [buf][ K 4096 halves | V 4096 halves ], 2 buffers = 32 KB
    __shared__ __attribute__((aligned(16))) _Float16 KV[2][8192];

    const int t   = threadIdx.x;
    const int l   = t & 63;
    const int w   = t >> 6;     // wave id 0..3
    const int q15 = l & 15;     // q col within wave's 16 rows (C-layout col)
    const int g   = l >> 4;     // lane group 0..3
    const int swz = (q15 & 7) << 3;

    const int bid = blockIdx.x;
    int b, qt, s;
    if (nsplit == 8) {
        // co-resident blocks {bid+256k}: s=k&7 (all splits), b=(m+k)&15
        const int k4 = bid >> 8;            // 0..15
        s  = k4 & 7;
        b  = (((bid >> 4) & 15) + k4) & 15;
        qt = (bid & 15) | ((k4 >> 3) << 4);
    } else {
        b  = ((bid & 15) + 8 * (bid >> 8)) & 15;
        qt = (bid >> 4) & 31;
        s  = 0;
    }

    const int valid = vn[b];
    const int nkt   = (valid + KB - 1) / KB;
    const int kt0   = s * tps;
    if (kt0 >= nkt) return;                  // block-uniform early out
    const int kt1   = min(nkt, kt0 + tps);

    const int qrow = qt * QB + w * 16 + q15;

    // fold 1/sqrt(D)=1/8 and log2(e) into Q: scores land in log2 units
    const float QS = 0.18033688011112042f;

    half8 qf[2];
    {
        const float* qp = qg + ((size_t)b * SLQ + qrow) * DH;
#pragma unroll
        for (int ss = 0; ss < 2; ++ss) {
            const int d0 = 8 * g + 32 * ss;
            f32x4 x = *(const f32x4*)(qp + d0);
            f32x4 y = *(const f32x4*)(qp + d0 + 4);
            half8 h;
#pragma unroll
            for (int i = 0; i < 4; ++i) {
                h[i]     = (_Float16)(x[i] * QS);
                h[i + 4] = (_Float16)(y[i] * QS);
            }
            qf[ss] = h;
        }
    }

    f32x4 acc[4];
#pragma unroll
    for (int i = 0; i < 4; ++i) acc[i] = f32x4{0.f, 0.f, 0.f, 0.f};
    float m = -1e30f, lsum = 0.f;

    const _Float16* kbase = k16 + (size_t)(b << 5) * 4096;
    const _Float16* vbase = v16 + (size_t)(b << 5) * 4096;

    // reg staging: thread t owns chunks t and t+256 of each tile (16B chunks;
    // lane stride 16B on ds_write => 2-way bank aliasing, free)
    uint4 rk0, rk1, rv0, rv1;
#define LOADREGS(KT)                                                         \
    {                                                                        \
        const uint4* kp_ = (const uint4*)(kbase + (size_t)(KT) * 4096);      \
        const uint4* vp_ = (const uint4*)(vbase + (size_t)(KT) * 4096);      \
        rk0 = kp_[t]; rk1 = kp_[t + 256];                                    \
        rv0 = vp_[t]; rv1 = vp_[t + 256];                                    \
    }
#define WRITEKV(CUR)                                                         \
    {                                                                        \
        uint4* kl_ = (uint4*)&KV[CUR][0];                                    \
        uint4* vl_ = (uint4*)&KV[CUR][4096];                                 \
        kl_[t] = rk0; kl_[t + 256] = rk1;                                    \
        vl_[t] = rv0; vl_[t + 256] = rv1;                                    \
    }

    LOADREGS(kt0);
    int cur = 0;

    for (int kt = kt0; kt < kt1; ++kt) {
        // write staged regs to buf[cur]; barrier makes them visible AND
        // guarantees buf[cur] readers from 2 iters ago are done (disjoint
        // buffers handle the 1-iter-ago case). Loads below never cross a
        // barrier: issued after this one, consumed before the next.
        WRITEKV(cur);
        __syncthreads();
        if (kt + 1 < kt1) LOADREGS(kt + 1);   // hides under compute

        const _Float16* Kc = &KV[cur][0];
        const _Float16* Vc = &KV[cur][4096];

        // ---- QK^T (swapped): st[mt] C-layout: col=q15, row=key 16mt+4g+r
        f32x4 st[4];
        __builtin_amdgcn_s_setprio(1);
#pragma unroll
        for (int mt = 0; mt < 4; ++mt) {
            f32x4 c = f32x4{0.f, 0.f, 0.f, 0.f};
#pragma unroll
            for (int ss = 0; ss < 2; ++ss) {
                half8 a = *(const half8*)&Kc[(16 * mt + q15) * 64 + ((8 * g + 32 * ss) ^ swz)];
                c = __builtin_amdgcn_mfma_f32_16x16x32_f16(a, qf[ss], c, 0, 0, 0);
            }
            st[mt] = c;
        }
        __builtin_amdgcn_s_setprio(0);

        // ---- mask the (only) partial boundary tile
        const int krem = valid - kt * KB;
        if (krem < KB) {
#pragma unroll
            for (int mt = 0; mt < 4; ++mt)
#pragma unroll
                for (int r = 0; r < 4; ++r)
                    if (16 * mt + 4 * g + r >= krem) st[mt][r] = -1e30f;
        }

        // ---- tile max: pairwise tree (short dep chain)
        float x0 = fmaxf(fmaxf(st[0][0], st[0][1]), fmaxf(st[0][2], st[0][3]));
        float x1 = fmaxf(fmaxf(st[1][0], st[1][1]), fmaxf(st[1][2], st[1][3]));
        float x2 = fmaxf(fmaxf(st[2][0], st[2][1]), fmaxf(st[2][2], st[2][3]));
        float x3 = fmaxf(fmaxf(st[3][0], st[3][1]), fmaxf(st[3][2], st[3][3]));
        float tmax = fmaxf(fmaxf(x0, x1), fmaxf(x2, x3));
        tmax = fmaxf(tmax, __shfl_xor(tmax, 16));
        tmax = fmaxf(tmax, __shfl_xor(tmax, 32));

        // ---- T13 defer-max: skip rescale while growth <= 12 (P <= 2^12 f16-safe)
        if (!__all(tmax - m <= 12.0f)) {
            const float mn = fmaxf(m, tmax);
            const float sc = __builtin_amdgcn_exp2f(m - mn);
            lsum *= sc;
#pragma unroll
            for (int mt = 0; mt < 4; ++mt) acc[mt] *= sc;
            m = mn;
        }

        float p[4][4];
#pragma unroll
        for (int mt = 0; mt < 4; ++mt)
#pragma unroll
            for (int r = 0; r < 4; ++r)
                p[mt][r] = __builtin_amdgcn_exp2f(st[mt][r] - m);

        // pairwise sum tree
        float s0 = (p[0][0] + p[0][1]) + (p[0][2] + p[0][3]);
        float s1 = (p[1][0] + p[1][1]) + (p[1][2] + p[1][3]);
        float s2 = (p[2][0] + p[2][1]) + (p[2][2] + p[2][3]);
        float s3 = (p[3][0] + p[3][1]) + (p[3][2] + p[3][3]);
        float ps = (s0 + s1) + (s2 + s3);
        ps += __shfl_xor(ps, 16);
        ps += __shfl_xor(ps, 32);
        lsum += ps;

        half2t pk[4][2];
#pragma unroll
        for (int mt = 0; mt < 4; ++mt)
#pragma unroll
            for (int rr = 0; rr < 2; ++rr)
                pk[mt][rr] = pkrtz(p[mt][2 * rr], p[mt][2 * rr + 1]);

        // ---- PV: out^T += Vt * P^T (slot-consistent, no shuffles)
        __builtin_amdgcn_s_setprio(1);
#pragma unroll
        for (int ss = 0; ss < 2; ++ss) {
            union { half2t h2[4]; half8 v; } bf;
            bf.h2[0] = pk[2 * ss][0];
            bf.h2[1] = pk[2 * ss][1];
            bf.h2[2] = pk[2 * ss + 1][0];
            bf.h2[3] = pk[2 * ss + 1][1];
#pragma unroll
            for (int mt = 0; mt < 4; ++mt) {
                union { half4 h4[2]; half8 v; } af;
                af.h4[0] = *(const half4*)&Vc[(16 * mt + q15) * 64 + ((32 * ss + 4 * g) ^ swz)];
                af.h4[1] = *(const half4*)&Vc[(16 * mt + q15) * 64 + ((32 * ss + 16 + 4 * g) ^ swz)];
                acc[mt] = __builtin_amdgcn_mfma_f32_16x16x32_f16(af.v, bf.v, acc[mt], 0, 0, 0);
            }
        }
        __builtin_amdgcn_s_setprio(0);
        cur ^= 1;
    }
#undef LOADREGS
#undef WRITEKV

    // ---- epilogue: normalized f16 acc + (m,l) to workspace
    const float inv = 1.0f / lsum;
    const size_t row = (size_t)b * SLQ + qrow;
    _Float16* wp = ws_acc + ((size_t)s * NB * SLQ + row) * DH;
#pragma unroll
    for (int mt = 0; mt < 4; ++mt) {
        union { half2t h2[2]; uint2 u; } o;
        o.h2[0] = pkrtz(acc[mt][0] * inv, acc[mt][1] * inv);
        o.h2[1] = pkrtz(acc[mt][2] * inv, acc[mt][3] * inv);
        *(uint2*)(wp + 16 * mt + 4 * g) = o.u;
    }
    if (g == 0)
        *(float2*)(ws_ml + ((size_t)s * NB * SLQ + row) * 2) = make_float2(m, lsum);
}

// ---------------- combine ----------------------------------------------------
__global__ __launch_bounds__(256)
void attn_combine(const _Float16* __restrict__ ws_acc, const float* __restrict__ ws_ml,
                  const int* __restrict__ vn, float* __restrict__ og,
                  int nsplit, int tps)
{
    const int tid = blockIdx.x * 256 + threadIdx.x;
    const int row = tid >> 2;
    const int dq  = (tid & 3) << 4;
    const int b   = row >> 11;

    const int valid = vn[b];
    const int nkt   = (valid + KB - 1) / KB;
    const int nact  = min(nsplit, (nkt + tps - 1) / tps);

    float M = -1e30f;
    for (int s = 0; s < nact; ++s)
        M = fmaxf(M, ws_ml[((size_t)s * NB * SLQ + row) * 2]);

    float L = 0.f;
    f32x4 o[4];
#pragma unroll
    for (int i = 0; i < 4; ++i) o[i] = f32x4{0.f, 0.f, 0.f, 0.f};

    for (int s = 0; s < nact; ++s) {
        const float2 ml = *(const float2*)(ws_ml + ((size_t)s * NB * SLQ + row) * 2);
        const float wl = __builtin_amdgcn_exp2f(ml.x - M) * ml.y;  // weight * l_s
        L += wl;
        const _Float16* ap = ws_acc + ((size_t)s * NB * SLQ + row) * DH + dq;
        half8 h0 = ((const half8*)ap)[0];
        half8 h1 = ((const half8*)ap)[1];
#pragma unroll
        for (int r = 0; r < 4; ++r) {
            o[0][r] += wl * (float)h0[r];
            o[1][r] += wl * (float)h0[4 + r];
            o[2][r] += wl * (float)h1[r];
            o[3][r] += wl * (float)h1[4 + r];
        }
    }

    const float inv = 1.0f / L;
    float* op = og + (size_t)row * DH + dq;
#pragma unroll
    for (int i = 0; i < 4; ++i) {
        f32x4 r = o[i] * inv;
        *(f32x4*)(op + 4 * i) = r;
    }
}

} // namespace

extern "C" void kernel_launch(void* const* d_in, const int* in_sizes, int n_in,
                              void* d_out, int out_size, void* d_ws, size_t ws_size,
                              hipStream_t stream)
{
    const float* q    = (const float*)d_in[0];
    const float* k    = (const float*)d_in[1];
    const float* v    = (const float*)d_in[2];
    const int*   vnum = (const int*)d_in[3];
    float* out = (float*)d_out;

    const size_t k16H  = (size_t)NB * SLK * DH;         // 2.10M halves (4 MB)
    const size_t v16H  = k16H;
    const size_t rowsH = (size_t)NB * SLQ;              // 32768 q-rows

    // choose split count by workspace budget (~44 MB for nsplit=8)
    int nsplit = 8;
    {
        const size_t need8 = (k16H + v16H + (size_t)8 * rowsH * DH) * 2
                           + (size_t)8 * rowsH * 2 * 4;
        if (ws_size < need8) nsplit = 1;                // 12.5 MB fallback
    }
    const int tps = (nsplit == 8) ? 4 : 32;

    _Float16* k16    = (_Float16*)d_ws;
    _Float16* v16t   = k16 + k16H;
    _Float16* ws_acc = v16t + v16H;
    float*    ws_ml  = (float*)(ws_acc + (size_t)nsplit * rowsH * DH);

    prepass<<<dim3(NB * (SLK / KB)), dim3(256), 0, stream>>>(k, v, k16, v16t);

    dim3 gfwd(nsplit == 8 ? 4096 : 512);
    attn_fwd<<<gfwd, dim3(256), 0, stream>>>(q, k16, v16t, vnum, ws_acc, ws_ml,
                                             nsplit, tps);

    attn_combine<<<dim3((NB * SLQ * 4) / 256), dim3(256), 0, stream>>>(
        ws_acc, ws_ml, vnum, out, nsplit, tps);
}